// Round 17
// baseline (191.696 us; speedup 1.0000x reference)
//
#include <hip/hip_runtime.h>
#include <hip/hip_bf16.h>

// B=4, T=2048, D=1024, H=16, DK=DV=64
#define TT 2048

typedef __attribute__((ext_vector_type(8))) short bf16x8;
typedef __attribute__((ext_vector_type(4))) short s16x4;
typedef __attribute__((ext_vector_type(4))) float f32x4;
typedef __attribute__((ext_vector_type(16))) float f32x16;
typedef __attribute__((ext_vector_type(4))) unsigned int u32x4;

__device__ __forceinline__ unsigned short f2bf(float x) {
    unsigned u = __float_as_uint(x);
    return (unsigned short)((u + 0x7fffu + ((u >> 16) & 1u)) >> 16);
}

// Raw hardware 2^x (bit-identical to OCML exp2 for |x| < 126; compiler
// inserts the trans-op hazard wait-states for the builtin).
__device__ __forceinline__ float fast_exp2(float x) {
#if __has_builtin(__builtin_amdgcn_exp2f)
    return __builtin_amdgcn_exp2f(x);
#else
    return exp2f(x);
#endif
}

typedef __attribute__((address_space(1))) const unsigned int g_u32;
typedef __attribute__((address_space(3))) unsigned int l_u32;
__device__ __forceinline__ void gll16(const void* g, void* l) {
    __builtin_amdgcn_global_load_lds((g_u32*)g, (l_u32*)l, 16, 0, 0);
}

// scale/sqrt(dk) * log2(e), folded into Q so attention P = exp2(e) directly
#define QSCALE 0.1803368801111244f

// ---------------------------------------------------------------------------
// Weight transpose+convert only (activations now read fp32 directly by the
// GEMMs — R16's null result showed F32A staging ~= bf16 staging, so the
// conv round-trip for q/k was pure overhead). 1024 blocks, flat decode.
// ---------------------------------------------------------------------------
__global__ __launch_bounds__(256) void conv_w_kernel(
    const float* __restrict__ W0, const float* __restrict__ W1,
    const float* __restrict__ W2, const float* __restrict__ W3,
    short* __restrict__ Wt) {
    const int tid = threadIdx.x;
    const int flat = blockIdx.x;
    __shared__ short t[64][72];
    const int z = flat >> 8;           // 0..3
    const int by = (flat >> 4) & 15;   // d-tile
    const int bx = flat & 15;          // n-tile (or head)
    const float* W = (z == 0) ? W0 : (z == 1) ? W1 : (z == 2) ? W2 : W3;
    short* dst = Wt + (size_t)z * 1024 * 1024;
    const int d0 = by * 64;
    {
        const int r = tid >> 2;
        const int c0 = (tid & 3) * 16;
        const float* srow = (z < 3)
                                ? (W + (size_t)bx * 65536 + (size_t)(d0 + r) * 64 + c0)
                                : (W + (size_t)(d0 + r) * 1024 + bx * 64 + c0);
#pragma unroll
        for (int p = 0; p < 4; ++p) {
            const float4 v = *(const float4*)(srow + p * 4);
            t[r][c0 + p * 4 + 0] = (short)f2bf(v.x);
            t[r][c0 + p * 4 + 1] = (short)f2bf(v.y);
            t[r][c0 + p * 4 + 2] = (short)f2bf(v.z);
            t[r][c0 + p * 4 + 3] = (short)f2bf(v.w);
        }
    }
    __syncthreads();
    {
        const int j = tid >> 2;
        const int c0 = (tid & 3) * 16;
        bf16x8 v0, v1;
#pragma unroll
        for (int p = 0; p < 8; ++p) v0[p] = t[c0 + p][j];
#pragma unroll
        for (int p = 0; p < 8; ++p) v1[p] = t[c0 + 8 + p][j];
        short* drow = dst + (size_t)(bx * 64 + j) * 1024 + d0 + c0;
        *(bf16x8*)drow = v0;
        *(bf16x8*)(drow + 8) = v1;
    }
}

// ---------------------------------------------------------------------------
// Shared GEMM main loop (128x128x64, 4 waves). F32A: A is fp32; all 8
// global float4 loads issued before cvt/ds_write (one exposed latency).
// ---------------------------------------------------------------------------
template <bool F32A>
__device__ __forceinline__ void gemm_core(const void* __restrict__ Ap,
                                          const short* __restrict__ Bt,
                                          int m0, int n0, int tid,
                                          short* As, short* Bs, f32x4 acc[4][4]) {
    const int w = tid >> 6, lane = tid & 63;
    const int l16 = lane & 15, lk = lane >> 4;
    const int wr = w >> 1, wc = w & 1;
    const int srow = lane >> 3;
    const int schk = lane & 7;
#pragma unroll
    for (int i = 0; i < 4; ++i)
#pragma unroll
        for (int j = 0; j < 4; ++j)
#pragma unroll
            for (int r = 0; r < 4; ++r) acc[i][j][r] = 0.f;

    for (int k0 = 0; k0 < 1024; k0 += 64) {
        if constexpr (!F32A) {
#pragma unroll
            for (int p = 0; p < 4; ++p) {
                const int row = p * 32 + w * 8 + srow;
                const int ca = schk ^ (row & 7);
                gll16(Bt + (size_t)(n0 + row) * 1024 + k0 + ca * 8,
                      &Bs[p * 2048 + w * 512]);
                gll16((const short*)Ap + (size_t)(m0 + row) * 1024 + k0 + ca * 8,
                      &As[p * 2048 + w * 512]);
            }
        } else {
            // (1) async B staging first
#pragma unroll
            for (int p = 0; p < 4; ++p) {
                const int row = p * 32 + w * 8 + srow;
                const int ca = schk ^ (row & 7);
                gll16(Bt + (size_t)(n0 + row) * 1024 + k0 + ca * 8,
                      &Bs[p * 2048 + w * 512]);
            }
            // (2) issue ALL 8 A loads (overlapped latencies)
            float4 st[8];
#pragma unroll
            for (int p = 0; p < 4; ++p) {
                const int row = p * 32 + w * 8 + srow;
                const int ca = schk ^ (row & 7);
                const float* src =
                    (const float*)Ap + (size_t)(m0 + row) * 1024 + k0 + ca * 8;
                st[2 * p] = *(const float4*)src;
                st[2 * p + 1] = *(const float4*)(src + 4);
            }
            // (3) convert + LDS write
#pragma unroll
            for (int p = 0; p < 4; ++p) {
                const float4 lo = st[2 * p];
                const float4 hi = st[2 * p + 1];
                unsigned u0, u1, u2, u3;
                asm("v_cvt_pk_bf16_f32 %0, %1, %2" : "=v"(u0) : "v"(lo.x), "v"(lo.y));
                asm("v_cvt_pk_bf16_f32 %0, %1, %2" : "=v"(u1) : "v"(lo.z), "v"(lo.w));
                asm("v_cvt_pk_bf16_f32 %0, %1, %2" : "=v"(u2) : "v"(hi.x), "v"(hi.y));
                asm("v_cvt_pk_bf16_f32 %0, %1, %2" : "=v"(u3) : "v"(hi.z), "v"(hi.w));
                u32x4 pk;
                pk[0] = u0; pk[1] = u1; pk[2] = u2; pk[3] = u3;
                *(u32x4*)&As[p * 2048 + w * 512 + lane * 8] = pk;
            }
        }
        __syncthreads();
#pragma unroll
        for (int kc = 0; kc < 2; ++kc) {
            bf16x8 a[4], b[4];
#pragma unroll
            for (int mi = 0; mi < 4; ++mi) {
                const int row = wr * 64 + mi * 16 + l16;
                a[mi] = *(const bf16x8*)&As[row * 64 + (((kc * 4 + lk) ^ (row & 7)) * 8)];
            }
#pragma unroll
            for (int ni = 0; ni < 4; ++ni) {
                const int row = wc * 64 + ni * 16 + l16;
                b[ni] = *(const bf16x8*)&Bs[row * 64 + (((kc * 4 + lk) ^ (row & 7)) * 8)];
            }
#pragma unroll
            for (int mi = 0; mi < 4; ++mi)
#pragma unroll
                for (int ni = 0; ni < 4; ++ni)
                    acc[mi][ni] = __builtin_amdgcn_mfma_f32_16x16x32_bf16(
                        a[mi], b[ni], acc[mi][ni], 0, 0, 0);
        }
        __syncthreads();
    }
}

// ---------------------------------------------------------------------------
// Q, K and V projections in ONE launch (grid.z = 0:Q, 1:K, 2:V), all three
// reading the fp32 activations directly (F32A staging).
// ---------------------------------------------------------------------------
__global__ __launch_bounds__(256) void gemm_qkv_kernel(
    const float* __restrict__ Qf, const float* __restrict__ Kf,
    const float* __restrict__ Vf, const short* __restrict__ Wt,
    const float* __restrict__ bq, const float* __restrict__ bk,
    const float* __restrict__ bv, short* __restrict__ Qp,
    short* __restrict__ Kp, short* __restrict__ VTp) {
    __shared__ short As[8192];
    __shared__ short Bs[8192];
    const int z = blockIdx.z;
    const int id = blockIdx.x;
    const int swz = (id & 7) * 64 + (id >> 3);
    const int n0 = (swz & 7) * 128;
    const int m0 = (swz >> 3) * 128;
    const int tid = threadIdx.x;
    const int w = tid >> 6, lane = tid & 63;
    const int l16 = lane & 15, lk = lane >> 4;
    const int wr = w >> 1, wc = w & 1;
    const size_t WSEG = (size_t)1024 * 1024;

    f32x4 acc[4][4];
    if (z == 0)
        gemm_core<true>(Qf, Wt, m0, n0, tid, As, Bs, acc);
    else if (z == 1)
        gemm_core<true>(Kf, Wt + WSEG, m0, n0, tid, As, Bs, acc);
    else
        gemm_core<true>(Vf, Wt + 2 * WSEG, m0, n0, tid, As, Bs, acc);

    const float* bias = (z == 0) ? bq : (z == 1) ? bk : bv;
#pragma unroll
    for (int mi = 0; mi < 4; ++mi) {
        const int gm0 = m0 + wr * 64 + mi * 16 + lk * 4;
#pragma unroll
        for (int ni = 0; ni < 4; ++ni) {
            const int gn = n0 + wc * 64 + ni * 16 + l16;
            const float bv_ = bias[gn];
            if (z == 0) {
                const float bvs = bv_ * QSCALE;
#pragma unroll
                for (int r = 0; r < 4; ++r) {
                    const int gm = gm0 + r;
                    Qp[((size_t)((gm >> 11) * 16 + (gn >> 6)) * 2048 + (gm & 2047)) * 64 +
                       (gn & 63)] = (short)f2bf(fmaf(acc[mi][ni][r], QSCALE, bvs));
                }
            } else if (z == 1) {
#pragma unroll
                for (int r = 0; r < 4; ++r) {
                    const int gm = gm0 + r;
                    const int t = gm & 2047;
                    const int j = gn & 63;
                    const int jsw = (((j >> 3) ^ (t & 7)) << 3) | (j & 7);
                    Kp[((size_t)((gm >> 11) * 16 + (gn >> 6)) * 2048 + t) * 64 + jsw] =
                        (short)f2bf(acc[mi][ni][r] + bv_);
                }
            } else {  // V -> VT, pack 4 consecutive t
                s16x4 pk;
#pragma unroll
                for (int r = 0; r < 4; ++r) pk[r] = (short)f2bf(acc[mi][ni][r] + bv_);
                const int t0 = gm0 & 2047;
                const int j = gn & 63;
                const int tsw = (t0 & ~63) | ((((t0 >> 3) & 7) ^ (j & 7)) << 3) | (t0 & 7);
                *(s16x4*)&VTp[(((size_t)((gm0 >> 11) * 16 + (gn >> 6))) * 64 + j) * 2048 +
                              tsw] = pk;
            }
        }
    }
}

// ---------------------------------------------------------------------------
// Final output projection: fp32 out [m][n]
// ---------------------------------------------------------------------------
__global__ __launch_bounds__(256) void gemm_out_kernel(
    const short* __restrict__ A, const short* __restrict__ Bt,
    const float* __restrict__ bias, float* __restrict__ outf) {
    __shared__ short As[8192];
    __shared__ short Bs[8192];
    const int id = blockIdx.x;
    const int swz = (id & 7) * 64 + (id >> 3);
    const int n0 = (swz & 7) * 128;
    const int m0 = (swz >> 3) * 128;
    const int tid = threadIdx.x;
    const int w = tid >> 6, lane = tid & 63;
    const int l16 = lane & 15, lk = lane >> 4;
    const int wr = w >> 1, wc = w & 1;

    f32x4 acc[4][4];
    gemm_core<false>(A, Bt, m0, n0, tid, As, Bs, acc);

#pragma unroll
    for (int mi = 0; mi < 4; ++mi) {
        const int gm0 = m0 + wr * 64 + mi * 16 + lk * 4;
#pragma unroll
        for (int ni = 0; ni < 4; ++ni) {
            const int gn = n0 + wc * 64 + ni * 16 + l16;
            const float bv = bias[gn];
#pragma unroll
            for (int r = 0; r < 4; ++r)
                outf[(size_t)(gm0 + r) * 1024 + gn] = acc[mi][ni][r] + bv;
        }
    }
}

// ---------------------------------------------------------------------------
// Attention per-tile compute, NB = compile-time buffer index so every
// ds_read is base-pointer + immediate.
// ---------------------------------------------------------------------------
template <int NB>
__device__ __forceinline__ void attn_tile(const short* __restrict__ smf,
                                          const int* __restrict__ ro,
                                          const bf16x8* __restrict__ qf,
                                          f32x16* __restrict__ acc,
                                          float& ts_acc) {
    u32x4 pa[4];  // PV A-frags
#pragma unroll
    for (int sb = 0; sb < 2; ++sb) {
        f32x16 e;
#pragma unroll
        for (int r = 0; r < 16; ++r) e[r] = 0.f;
        __builtin_amdgcn_s_setprio(1);
#pragma unroll
        for (int sl = 0; sl < 4; ++sl) {
            const bf16x8 kf = *(const bf16x8*)&smf[ro[sb * 4 + sl] + NB * 8192];
            e = __builtin_amdgcn_mfma_f32_32x32x16_bf16(kf, qf[sl], e, 0, 0, 0);
        }
        __builtin_amdgcn_s_setprio(0);
        // p = exp2(e); rows held: s = (reg&3) + 8*(reg>>2) + 4*hi (+32*sb)
        float p[16];
#pragma unroll
        for (int r = 0; r < 16; ++r) p[r] = fast_exp2(e[r]);
#pragma unroll
        for (int r = 0; r < 16; r += 4)
            ts_acc += ((p[r] + p[r + 1]) + (p[r + 2] + p[r + 3]));
        unsigned u[4][2];
#pragma unroll
        for (int A = 0; A < 4; ++A)
#pragma unroll
            for (int b = 0; b < 2; ++b)
                asm("v_cvt_pk_bf16_f32 %0, %1, %2"
                    : "=v"(u[A][b])
                    : "v"(p[4 * A + 2 * b]), "v"(p[4 * A + 2 * b + 1]));
#pragma unroll
        for (int k1 = 0; k1 < 2; ++k1) {
#pragma unroll
            for (int b = 0; b < 2; ++b) {
                unsigned p0 = u[2 * k1][b], p1 = u[2 * k1 + 1][b];
                asm("v_permlane32_swap_b32 %0, %1" : "+v"(p0), "+v"(p1));
                pa[sb * 2 + k1][b] = p0;
                pa[sb * 2 + k1][2 + b] = p1;
            }
        }
    }
    // PV: A = P (row q = l31, k = s), B = V^T tile (col v = l31)
    __builtin_amdgcn_s_setprio(1);
#pragma unroll
    for (int vb = 0; vb < 2; ++vb) {
#pragma unroll
        for (int ks = 0; ks < 4; ++ks) {
            const bf16x8 vf =
                *(const bf16x8*)&smf[ro[vb * 4 + ks] + NB * 8192 + 4096];
            const bf16x8 paf = __builtin_bit_cast(bf16x8, pa[ks]);
            acc[vb] = __builtin_amdgcn_mfma_f32_32x32x16_bf16(paf, vf, acc[vb],
                                                              0, 0, 0);
        }
    }
    __builtin_amdgcn_s_setprio(0);
}

// ---------------------------------------------------------------------------
// Flash attention — R15 kernel unchanged (raw v_exp_f32, hoisted LDS
// addressing, double-buffered prefetch, 512 thr x 512 blocks).
// ---------------------------------------------------------------------------
__global__ __launch_bounds__(512, 4) void attn_kernel(
    const short* __restrict__ Qp, const short* __restrict__ Kp,
    const short* __restrict__ VTp, short* __restrict__ heads) {
    __shared__ short smem[4][4096];  // [nb][kv][64x64 tile]
    short* smf = &smem[0][0];
    const int tid = threadIdx.x;
    const int w = tid >> 6, lane = tid & 63;
    const int l31 = lane & 31, hi = lane >> 5;
    const int id = blockIdx.x;
    const int swz = (id & 7) * 64 + (id >> 3);  // 512 blocks, XCD-contiguous
    const int qbase = (swz & 7) * 256;          // 8 blocks per bh
    const int bh = swz >> 3;
    const size_t kvbase = (size_t)bh * TT * 64;

    // Q B-fragments: col q = l31, k(d) = sl*16 + hi*8 + j
    bf16x8 qf[4];
    {
        const short* Qw = Qp + kvbase + (size_t)(qbase + w * 32 + l31) * 64 + hi * 8;
#pragma unroll
        for (int sl = 0; sl < 4; ++sl) qf[sl] = *(const bf16x8*)(Qw + sl * 16);
    }

    f32x16 acc[2];
#pragma unroll
    for (int vb = 0; vb < 2; ++vb)
#pragma unroll
        for (int r = 0; r < 16; ++r) acc[vb][r] = 0.f;
    float ts_acc = 0.f;  // per-lane partial of sum_s P[q=l31][s]

    // per-lane read offsets, slot (sb,sl): (sb*32+l31)*64 + ((sl*2+hi)^(l31&7))*8
    int ro[8];
#pragma unroll
    for (int sb = 0; sb < 2; ++sb)
#pragma unroll
        for (int sl = 0; sl < 4; ++sl)
            ro[sb * 4 + sl] =
                (sb * 32 + l31) * 64 + (((sl * 2 + hi) ^ (l31 & 7)) * 8);

    // staging: incrementing global pointers; LDS dst compile-time per phase
    const int strow = w * 8 + (lane >> 3);
    const int sca = lane & 7;  // source pre-swizzled -> linear copy
    const short* gK = Kp + kvbase + (size_t)strow * 64 + sca * 8;    // +4096/tile
    const short* gV = VTp + kvbase + (size_t)strow * 2048 + sca * 8; // +64/tile
    short* lK0 = smf + 0 + w * 512;
    short* lV0 = smf + 4096 + w * 512;
    short* lK1 = smf + 8192 + w * 512;
    short* lV1 = smf + 12288 + w * 512;

    // prologue: stage tile 0 into buf0
    gll16(gK, lK0);
    gll16(gV, lV0);
    __syncthreads();

    for (int it = 0; it < 16; ++it) {
        // phase 0: stage tile 2it+1 -> buf1, compute buf0 (tile 2it)
        gK += 4096;
        gV += 64;
        gll16(gK, lK1);
        gll16(gV, lV1);
        attn_tile<0>(smf, ro, qf, acc, ts_acc);
        __syncthreads();
        // phase 1: stage tile 2it+2 -> buf0 (unless done), compute buf1
        if (it < 15) {
            gK += 4096;
            gV += 64;
            gll16(gK, lK0);
            gll16(gV, lV0);
        }
        attn_tile<1>(smf, ro, qf, acc, ts_acc);
        __syncthreads();
    }

    // l per q: combine wave halves (lane q and q+32 hold the two halves)
    float l = ts_acc;
    l += __shfl_xor(l, 32);
    const float linv = 1.0f / l;
    const int b_ = bh >> 4, h = bh & 15;
#pragma unroll
    for (int r = 0; r < 16; ++r) {
        const int qrow = (r & 3) + 8 * (r >> 2) + 4 * hi;
        const float inv = __shfl(linv, qrow);
        const int qg = qbase + w * 32 + qrow;
        const size_t base = ((size_t)(b_ * TT + qg)) * 1024 + h * 64 + l31;
        heads[base] = (short)f2bf(acc[0][r] * inv);
        heads[base + 32] = (short)f2bf(acc[1][r] * inv);
    }
}

extern "C" void kernel_launch(void* const* d_in, const int* in_sizes, int n_in,
                              void* d_out, int out_size, void* d_ws, size_t ws_size,
                              hipStream_t stream) {
    const float* q = (const float*)d_in[0];
    const float* k = (const float*)d_in[1];
    const float* v = (const float*)d_in[2];
    const float* Wq = (const float*)d_in[3];
    const float* bq = (const float*)d_in[4];
    const float* Wk = (const float*)d_in[5];
    const float* bk = (const float*)d_in[6];
    const float* Wv = (const float*)d_in[7];
    const float* bv = (const float*)d_in[8];
    const float* Wo = (const float*)d_in[9];
    const float* bo = (const float*)d_in[10];
    float* out = (float*)d_out;

    const size_t SEG = (size_t)4 * 16 * 2048 * 64;  // 8,388,608 bf16 elems
    // d_out (33.5 MB): Qp | Kp until the final GEMM overwrites with fp32 out.
    short* Qp = (short*)d_out;
    short* Kp = Qp + SEG;
    // ws: heads | Wt x4 | VTp  (= 41.6 MB)
    short* ws = (short*)d_ws;
    short* heads = ws;
    short* Wt = heads + SEG;
    short* VTp = Wt + (size_t)4 * 1024 * 1024;
    const size_t WSEG = (size_t)1024 * 1024;

    dim3 blk(256);

    conv_w_kernel<<<dim3(1024), blk, 0, stream>>>(Wq, Wk, Wv, Wo, Wt);
    gemm_qkv_kernel<<<dim3(512, 1, 3), blk, 0, stream>>>(q, k, v, Wt, bq, bk, bv,
                                                         Qp, Kp, VTp);
    attn_kernel<<<dim3(512), dim3(512), 0, stream>>>(Qp, Kp, VTp, heads);
    gemm_out_kernel<<<dim3(512), blk, 0, stream>>>(heads, Wt + 3 * WSEG, bo, out);
}

// Round 18
// 188.216 us; speedup vs baseline: 1.0185x; 1.0185x over previous
//
#include <hip/hip_runtime.h>
#include <hip/hip_bf16.h>

// B=4, T=2048, D=1024, H=16, DK=DV=64
#define TT 2048

typedef __attribute__((ext_vector_type(8))) short bf16x8;
typedef __attribute__((ext_vector_type(4))) short s16x4;
typedef __attribute__((ext_vector_type(4))) float f32x4;
typedef __attribute__((ext_vector_type(16))) float f32x16;
typedef __attribute__((ext_vector_type(4))) unsigned int u32x4;

__device__ __forceinline__ unsigned short f2bf(float x) {
    unsigned u = __float_as_uint(x);
    return (unsigned short)((u + 0x7fffu + ((u >> 16) & 1u)) >> 16);
}

// Raw hardware 2^x (bit-identical to OCML exp2 for |x| < 126).
__device__ __forceinline__ float fast_exp2(float x) {
#if __has_builtin(__builtin_amdgcn_exp2f)
    return __builtin_amdgcn_exp2f(x);
#else
    return exp2f(x);
#endif
}

typedef __attribute__((address_space(1))) const unsigned int g_u32;
typedef __attribute__((address_space(3))) unsigned int l_u32;
__device__ __forceinline__ void gll16(const void* g, void* l) {
    __builtin_amdgcn_global_load_lds((g_u32*)g, (l_u32*)l, 16, 0, 0);
}

// scale/sqrt(dk) * log2(e), folded into Q so attention P = exp2(e) directly
#define QSCALE 0.1803368801111244f

// ---------------------------------------------------------------------------
// Combined convert launch, grid (4096, 3):
//  y=0: q fp32 -> Xq bf16;  y=1: k fp32 -> Xk bf16
//  y=2: all four weights -> Wt[n][d] bf16 (first 1024 blocks; flat decode)
// (R17 lesson: all-F32A GEMMs regressed 40% — keep q,k pre-converted so
//  their GEMM slices use global_load_lds staging.)
// ---------------------------------------------------------------------------
__global__ __launch_bounds__(256) void conv_all_kernel(
    const float* __restrict__ q, short* __restrict__ Xq,
    const float* __restrict__ k, short* __restrict__ Xk,
    const float* __restrict__ W0, const float* __restrict__ W1,
    const float* __restrict__ W2, const float* __restrict__ W3,
    short* __restrict__ Wt, int n8) {
    const int tid = threadIdx.x;
    if (blockIdx.y < 2) {
        const int i = blockIdx.x * 256 + tid;
        if (i >= n8) return;
        const float* src = blockIdx.y ? k : q;
        short* dst = blockIdx.y ? Xk : Xq;
        const float4 a = ((const float4*)src)[2 * i];
        const float4 b = ((const float4*)src)[2 * i + 1];
        bf16x8 o;
        o[0] = (short)f2bf(a.x); o[1] = (short)f2bf(a.y);
        o[2] = (short)f2bf(a.z); o[3] = (short)f2bf(a.w);
        o[4] = (short)f2bf(b.x); o[5] = (short)f2bf(b.y);
        o[6] = (short)f2bf(b.z); o[7] = (short)f2bf(b.w);
        ((bf16x8*)dst)[i] = o;
        return;
    }
    // weights slice
    const int flat = blockIdx.x;
    if (flat >= 1024) return;
    __shared__ short t[64][72];
    const int z = flat >> 8;           // 0..3
    const int by = (flat >> 4) & 15;   // d-tile
    const int bx = flat & 15;          // n-tile (or head)
    const float* W = (z == 0) ? W0 : (z == 1) ? W1 : (z == 2) ? W2 : W3;
    short* dst = Wt + (size_t)z * 1024 * 1024;
    const int d0 = by * 64;
    {
        const int r = tid >> 2;
        const int c0 = (tid & 3) * 16;
        const float* srow = (z < 3)
                                ? (W + (size_t)bx * 65536 + (size_t)(d0 + r) * 64 + c0)
                                : (W + (size_t)(d0 + r) * 1024 + bx * 64 + c0);
#pragma unroll
        for (int p = 0; p < 4; ++p) {
            const float4 v = *(const float4*)(srow + p * 4);
            t[r][c0 + p * 4 + 0] = (short)f2bf(v.x);
            t[r][c0 + p * 4 + 1] = (short)f2bf(v.y);
            t[r][c0 + p * 4 + 2] = (short)f2bf(v.z);
            t[r][c0 + p * 4 + 3] = (short)f2bf(v.w);
        }
    }
    __syncthreads();
    {
        const int j = tid >> 2;
        const int c0 = (tid & 3) * 16;
        bf16x8 v0, v1;
#pragma unroll
        for (int p = 0; p < 8; ++p) v0[p] = t[c0 + p][j];
#pragma unroll
        for (int p = 0; p < 8; ++p) v1[p] = t[c0 + 8 + p][j];
        short* drow = dst + (size_t)(bx * 64 + j) * 1024 + d0 + c0;
        *(bf16x8*)drow = v0;
        *(bf16x8*)(drow + 8) = v1;
    }
}

// ---------------------------------------------------------------------------
// Shared GEMM main loop (128x128x64, 4 waves).
// bf16 path: DOUBLE-BUFFERED prefetch (attn-style) — stage tile t+1 into
// buf^1 before computing tile t; ONE barrier per tile. The old 2-barrier
// structure exposed the full load latency twice per K-iter with only
// 2 blocks/CU to hide it (measured ~4400 cy/iter vs ~800 compute).
// F32A path (V slice only): R16 single-buffer (uses buf0 only) — the
// reg-staged prefetch variant would push VGPR past 128.
// As/Bs are 16384 shorts each (2 x 16 KB buffers).
// ---------------------------------------------------------------------------
template <bool F32A>
__device__ __forceinline__ void gemm_core(const void* __restrict__ Ap,
                                          const short* __restrict__ Bt,
                                          int m0, int n0, int tid,
                                          short* As, short* Bs, f32x4 acc[4][4]) {
    const int w = tid >> 6, lane = tid & 63;
    const int l16 = lane & 15, lk = lane >> 4;
    const int wr = w >> 1, wc = w & 1;
    const int srow = lane >> 3;
    const int schk = lane & 7;
#pragma unroll
    for (int i = 0; i < 4; ++i)
#pragma unroll
        for (int j = 0; j < 4; ++j)
#pragma unroll
            for (int r = 0; r < 4; ++r) acc[i][j][r] = 0.f;

    auto COMPUTE = [&](int off) {
#pragma unroll
        for (int kc = 0; kc < 2; ++kc) {
            bf16x8 a[4], b[4];
#pragma unroll
            for (int mi = 0; mi < 4; ++mi) {
                const int row = wr * 64 + mi * 16 + l16;
                a[mi] = *(const bf16x8*)&As[off + row * 64 +
                                            (((kc * 4 + lk) ^ (row & 7)) * 8)];
            }
#pragma unroll
            for (int ni = 0; ni < 4; ++ni) {
                const int row = wc * 64 + ni * 16 + l16;
                b[ni] = *(const bf16x8*)&Bs[off + row * 64 +
                                            (((kc * 4 + lk) ^ (row & 7)) * 8)];
            }
#pragma unroll
            for (int mi = 0; mi < 4; ++mi)
#pragma unroll
                for (int ni = 0; ni < 4; ++ni)
                    acc[mi][ni] = __builtin_amdgcn_mfma_f32_16x16x32_bf16(
                        a[mi], b[ni], acc[mi][ni], 0, 0, 0);
        }
    };

    if constexpr (!F32A) {
        auto STAGE = [&](int k0, int off) {
#pragma unroll
            for (int p = 0; p < 4; ++p) {
                const int row = p * 32 + w * 8 + srow;
                const int ca = schk ^ (row & 7);
                gll16(Bt + (size_t)(n0 + row) * 1024 + k0 + ca * 8,
                      &Bs[off + p * 2048 + w * 512]);
                gll16((const short*)Ap + (size_t)(m0 + row) * 1024 + k0 + ca * 8,
                      &As[off + p * 2048 + w * 512]);
            }
        };
        STAGE(0, 0);
        __syncthreads();  // drains prologue loads
        for (int it = 0; it < 8; ++it) {
            STAGE(it * 128 + 64, 8192);   // prefetch tile 2it+1 -> buf1
            COMPUTE(0);                   // compute tile 2it from buf0
            __syncthreads();              // drain prefetch; buf0 free
            if (it < 7) STAGE(it * 128 + 128, 0);  // prefetch tile 2it+2
            COMPUTE(8192);                // compute tile 2it+1 from buf1
            __syncthreads();
        }
    } else {
        for (int k0 = 0; k0 < 1024; k0 += 64) {
            // (1) async B staging
#pragma unroll
            for (int p = 0; p < 4; ++p) {
                const int row = p * 32 + w * 8 + srow;
                const int ca = schk ^ (row & 7);
                gll16(Bt + (size_t)(n0 + row) * 1024 + k0 + ca * 8,
                      &Bs[p * 2048 + w * 512]);
            }
            // (2) issue all 8 A loads (overlapped latencies)
            float4 st[8];
#pragma unroll
            for (int p = 0; p < 4; ++p) {
                const int row = p * 32 + w * 8 + srow;
                const int ca = schk ^ (row & 7);
                const float* src =
                    (const float*)Ap + (size_t)(m0 + row) * 1024 + k0 + ca * 8;
                st[2 * p] = *(const float4*)src;
                st[2 * p + 1] = *(const float4*)(src + 4);
            }
            // (3) convert + LDS write
#pragma unroll
            for (int p = 0; p < 4; ++p) {
                const float4 lo = st[2 * p];
                const float4 hi = st[2 * p + 1];
                unsigned u0, u1, u2, u3;
                asm("v_cvt_pk_bf16_f32 %0, %1, %2" : "=v"(u0) : "v"(lo.x), "v"(lo.y));
                asm("v_cvt_pk_bf16_f32 %0, %1, %2" : "=v"(u1) : "v"(lo.z), "v"(lo.w));
                asm("v_cvt_pk_bf16_f32 %0, %1, %2" : "=v"(u2) : "v"(hi.x), "v"(hi.y));
                asm("v_cvt_pk_bf16_f32 %0, %1, %2" : "=v"(u3) : "v"(hi.z), "v"(hi.w));
                u32x4 pk;
                pk[0] = u0; pk[1] = u1; pk[2] = u2; pk[3] = u3;
                *(u32x4*)&As[p * 2048 + w * 512 + lane * 8] = pk;
            }
            __syncthreads();
            COMPUTE(0);
            __syncthreads();
        }
    }
}

// ---------------------------------------------------------------------------
// Q, K and V projections in ONE launch (grid.z = 0:Q, 1:K, 2:V).
// ---------------------------------------------------------------------------
__global__ __launch_bounds__(256) void gemm_qkv_kernel(
    const short* __restrict__ Xq, const short* __restrict__ Xk,
    const float* __restrict__ Vf, const short* __restrict__ Wt,
    const float* __restrict__ bq, const float* __restrict__ bk,
    const float* __restrict__ bv, short* __restrict__ Qp,
    short* __restrict__ Kp, short* __restrict__ VTp) {
    __shared__ short As[16384];
    __shared__ short Bs[16384];
    const int z = blockIdx.z;
    const int id = blockIdx.x;
    const int swz = (id & 7) * 64 + (id >> 3);
    const int n0 = (swz & 7) * 128;
    const int m0 = (swz >> 3) * 128;
    const int tid = threadIdx.x;
    const int w = tid >> 6, lane = tid & 63;
    const int l16 = lane & 15, lk = lane >> 4;
    const int wr = w >> 1, wc = w & 1;
    const size_t WSEG = (size_t)1024 * 1024;

    f32x4 acc[4][4];
    if (z == 0)
        gemm_core<false>(Xq, Wt, m0, n0, tid, As, Bs, acc);
    else if (z == 1)
        gemm_core<false>(Xk, Wt + WSEG, m0, n0, tid, As, Bs, acc);
    else
        gemm_core<true>(Vf, Wt + 2 * WSEG, m0, n0, tid, As, Bs, acc);

    const float* bias = (z == 0) ? bq : (z == 1) ? bk : bv;
#pragma unroll
    for (int mi = 0; mi < 4; ++mi) {
        const int gm0 = m0 + wr * 64 + mi * 16 + lk * 4;
#pragma unroll
        for (int ni = 0; ni < 4; ++ni) {
            const int gn = n0 + wc * 64 + ni * 16 + l16;
            const float bv_ = bias[gn];
            if (z == 0) {
                const float bvs = bv_ * QSCALE;
#pragma unroll
                for (int r = 0; r < 4; ++r) {
                    const int gm = gm0 + r;
                    Qp[((size_t)((gm >> 11) * 16 + (gn >> 6)) * 2048 + (gm & 2047)) * 64 +
                       (gn & 63)] = (short)f2bf(fmaf(acc[mi][ni][r], QSCALE, bvs));
                }
            } else if (z == 1) {
#pragma unroll
                for (int r = 0; r < 4; ++r) {
                    const int gm = gm0 + r;
                    const int t = gm & 2047;
                    const int j = gn & 63;
                    const int jsw = (((j >> 3) ^ (t & 7)) << 3) | (j & 7);
                    Kp[((size_t)((gm >> 11) * 16 + (gn >> 6)) * 2048 + t) * 64 + jsw] =
                        (short)f2bf(acc[mi][ni][r] + bv_);
                }
            } else {  // V -> VT, pack 4 consecutive t
                s16x4 pk;
#pragma unroll
                for (int r = 0; r < 4; ++r) pk[r] = (short)f2bf(acc[mi][ni][r] + bv_);
                const int t0 = gm0 & 2047;
                const int j = gn & 63;
                const int tsw = (t0 & ~63) | ((((t0 >> 3) & 7) ^ (j & 7)) << 3) | (t0 & 7);
                *(s16x4*)&VTp[(((size_t)((gm0 >> 11) * 16 + (gn >> 6))) * 64 + j) * 2048 +
                              tsw] = pk;
            }
        }
    }
}

// ---------------------------------------------------------------------------
// Final output projection: fp32 out [m][n]
// ---------------------------------------------------------------------------
__global__ __launch_bounds__(256) void gemm_out_kernel(
    const short* __restrict__ A, const short* __restrict__ Bt,
    const float* __restrict__ bias, float* __restrict__ outf) {
    __shared__ short As[16384];
    __shared__ short Bs[16384];
    const int id = blockIdx.x;
    const int swz = (id & 7) * 64 + (id >> 3);
    const int n0 = (swz & 7) * 128;
    const int m0 = (swz >> 3) * 128;
    const int tid = threadIdx.x;
    const int w = tid >> 6, lane = tid & 63;
    const int l16 = lane & 15, lk = lane >> 4;
    const int wr = w >> 1, wc = w & 1;

    f32x4 acc[4][4];
    gemm_core<false>(A, Bt, m0, n0, tid, As, Bs, acc);

#pragma unroll
    for (int mi = 0; mi < 4; ++mi) {
        const int gm0 = m0 + wr * 64 + mi * 16 + lk * 4;
#pragma unroll
        for (int ni = 0; ni < 4; ++ni) {
            const int gn = n0 + wc * 64 + ni * 16 + l16;
            const float bv = bias[gn];
#pragma unroll
            for (int r = 0; r < 4; ++r)
                outf[(size_t)(gm0 + r) * 1024 + gn] = acc[mi][ni][r] + bv;
        }
    }
}

// ---------------------------------------------------------------------------
// Attention per-tile compute, NB = compile-time buffer index.
// ---------------------------------------------------------------------------
template <int NB>
__device__ __forceinline__ void attn_tile(const short* __restrict__ smf,
                                          const int* __restrict__ ro,
                                          const bf16x8* __restrict__ qf,
                                          f32x16* __restrict__ acc,
                                          float& ts_acc) {
    u32x4 pa[4];  // PV A-frags
#pragma unroll
    for (int sb = 0; sb < 2; ++sb) {
        f32x16 e;
#pragma unroll
        for (int r = 0; r < 16; ++r) e[r] = 0.f;
        __builtin_amdgcn_s_setprio(1);
#pragma unroll
        for (int sl = 0; sl < 4; ++sl) {
            const bf16x8 kf = *(const bf16x8*)&smf[ro[sb * 4 + sl] + NB * 8192];
            e = __builtin_amdgcn_mfma_f32_32x32x16_bf16(kf, qf[sl], e, 0, 0, 0);
        }
        __builtin_amdgcn_s_setprio(0);
        float p[16];
#pragma unroll
        for (int r = 0; r < 16; ++r) p[r] = fast_exp2(e[r]);
#pragma unroll
        for (int r = 0; r < 16; r += 4)
            ts_acc += ((p[r] + p[r + 1]) + (p[r + 2] + p[r + 3]));
        unsigned u[4][2];
#pragma unroll
        for (int A = 0; A < 4; ++A)
#pragma unroll
            for (int b = 0; b < 2; ++b)
                asm("v_cvt_pk_bf16_f32 %0, %1, %2"
                    : "=v"(u[A][b])
                    : "v"(p[4 * A + 2 * b]), "v"(p[4 * A + 2 * b + 1]));
#pragma unroll
        for (int k1 = 0; k1 < 2; ++k1) {
#pragma unroll
            for (int b = 0; b < 2; ++b) {
                unsigned p0 = u[2 * k1][b], p1 = u[2 * k1 + 1][b];
                asm("v_permlane32_swap_b32 %0, %1" : "+v"(p0), "+v"(p1));
                pa[sb * 2 + k1][b] = p0;
                pa[sb * 2 + k1][2 + b] = p1;
            }
        }
    }
    __builtin_amdgcn_s_setprio(1);
#pragma unroll
    for (int vb = 0; vb < 2; ++vb) {
#pragma unroll
        for (int ks = 0; ks < 4; ++ks) {
            const bf16x8 vf =
                *(const bf16x8*)&smf[ro[vb * 4 + ks] + NB * 8192 + 4096];
            const bf16x8 paf = __builtin_bit_cast(bf16x8, pa[ks]);
            acc[vb] = __builtin_amdgcn_mfma_f32_32x32x16_bf16(paf, vf, acc[vb],
                                                              0, 0, 0);
        }
    }
    __builtin_amdgcn_s_setprio(0);
}

// ---------------------------------------------------------------------------
// Flash attention — R15/R16 kernel unchanged.
// ---------------------------------------------------------------------------
__global__ __launch_bounds__(512, 4) void attn_kernel(
    const short* __restrict__ Qp, const short* __restrict__ Kp,
    const short* __restrict__ VTp, short* __restrict__ heads) {
    __shared__ short smem[4][4096];  // [nb][kv][64x64 tile]
    short* smf = &smem[0][0];
    const int tid = threadIdx.x;
    const int w = tid >> 6, lane = tid & 63;
    const int l31 = lane & 31, hi = lane >> 5;
    const int id = blockIdx.x;
    const int swz = (id & 7) * 64 + (id >> 3);  // 512 blocks, XCD-contiguous
    const int qbase = (swz & 7) * 256;          // 8 blocks per bh
    const int bh = swz >> 3;
    const size_t kvbase = (size_t)bh * TT * 64;

    bf16x8 qf[4];
    {
        const short* Qw = Qp + kvbase + (size_t)(qbase + w * 32 + l31) * 64 + hi * 8;
#pragma unroll
        for (int sl = 0; sl < 4; ++sl) qf[sl] = *(const bf16x8*)(Qw + sl * 16);
    }

    f32x16 acc[2];
#pragma unroll
    for (int vb = 0; vb < 2; ++vb)
#pragma unroll
        for (int r = 0; r < 16; ++r) acc[vb][r] = 0.f;
    float ts_acc = 0.f;

    int ro[8];
#pragma unroll
    for (int sb = 0; sb < 2; ++sb)
#pragma unroll
        for (int sl = 0; sl < 4; ++sl)
            ro[sb * 4 + sl] =
                (sb * 32 + l31) * 64 + (((sl * 2 + hi) ^ (l31 & 7)) * 8);

    const int strow = w * 8 + (lane >> 3);
    const int sca = lane & 7;
    const short* gK = Kp + kvbase + (size_t)strow * 64 + sca * 8;    // +4096/tile
    const short* gV = VTp + kvbase + (size_t)strow * 2048 + sca * 8; // +64/tile
    short* lK0 = smf + 0 + w * 512;
    short* lV0 = smf + 4096 + w * 512;
    short* lK1 = smf + 8192 + w * 512;
    short* lV1 = smf + 12288 + w * 512;

    gll16(gK, lK0);
    gll16(gV, lV0);
    __syncthreads();

    for (int it = 0; it < 16; ++it) {
        gK += 4096;
        gV += 64;
        gll16(gK, lK1);
        gll16(gV, lV1);
        attn_tile<0>(smf, ro, qf, acc, ts_acc);
        __syncthreads();
        if (it < 15) {
            gK += 4096;
            gV += 64;
            gll16(gK, lK0);
            gll16(gV, lV0);
        }
        attn_tile<1>(smf, ro, qf, acc, ts_acc);
        __syncthreads();
    }

    float l = ts_acc;
    l += __shfl_xor(l, 32);
    const float linv = 1.0f / l;
    const int b_ = bh >> 4, h = bh & 15;
#pragma unroll
    for (int r = 0; r < 16; ++r) {
        const int qrow = (r & 3) + 8 * (r >> 2) + 4 * hi;
        const float inv = __shfl(linv, qrow);
        const int qg = qbase + w * 32 + qrow;
        const size_t base = ((size_t)(b_ * TT + qg)) * 1024 + h * 64 + l31;
        heads[base] = (short)f2bf(acc[0][r] * inv);
        heads[base + 32] = (short)f2bf(acc[1][r] * inv);
    }
}

extern "C" void kernel_launch(void* const* d_in, const int* in_sizes, int n_in,
                              void* d_out, int out_size, void* d_ws, size_t ws_size,
                              hipStream_t stream) {
    const float* q = (const float*)d_in[0];
    const float* k = (const float*)d_in[1];
    const float* v = (const float*)d_in[2];
    const float* Wq = (const float*)d_in[3];
    const float* bq = (const float*)d_in[4];
    const float* Wk = (const float*)d_in[5];
    const float* bk = (const float*)d_in[6];
    const float* Wv = (const float*)d_in[7];
    const float* bv = (const float*)d_in[8];
    const float* Wo = (const float*)d_in[9];
    const float* bo = (const float*)d_in[10];
    float* out = (float*)d_out;

    const size_t SEG = (size_t)4 * 16 * 2048 * 64;  // 8,388,608 bf16 elems
    // d_out (33.5 MB): Qp | Kp until the final GEMM overwrites with fp32 out.
    short* Qp = (short*)d_out;
    short* Kp = Qp + SEG;
    // ws: Xq | Xk | Wt x4 | VTp  (= 56 MB)
    short* ws = (short*)d_ws;
    short* Xq = ws;  // later reused for heads
    short* Xk = Xq + SEG;
    short* Wt = Xk + SEG;
    short* VTp = Wt + (size_t)4 * 1024 * 1024;
    const size_t WSEG = (size_t)1024 * 1024;

    dim3 blk(256);
    const int n8 = (int)(SEG / 8);

    conv_all_kernel<<<dim3((n8 + 255) / 256, 3), blk, 0, stream>>>(
        q, Xq, k, Xk, Wq, Wk, Wv, Wo, Wt, n8);
    gemm_qkv_kernel<<<dim3(512, 1, 3), blk, 0, stream>>>(Xq, Xk, v, Wt, bq, bk, bv,
                                                         Qp, Kp, VTp);
    attn_kernel<<<dim3(512), dim3(512), 0, stream>>>(Qp, Kp, VTp, Xq /*heads*/);
    gemm_out_kernel<<<dim3(512), blk, 0, stream>>>(Xq, Wt + 3 * WSEG, bo, out);
}

// Round 19
// 186.889 us; speedup vs baseline: 1.0257x; 1.0071x over previous
//
#include <hip/hip_runtime.h>
#include <hip/hip_bf16.h>

// B=4, T=2048, D=1024, H=16, DK=DV=64
#define TT 2048

typedef __attribute__((ext_vector_type(8))) short bf16x8;
typedef __attribute__((ext_vector_type(4))) short s16x4;
typedef __attribute__((ext_vector_type(4))) float f32x4;
typedef __attribute__((ext_vector_type(16))) float f32x16;
typedef __attribute__((ext_vector_type(4))) unsigned int u32x4;

__device__ __forceinline__ unsigned short f2bf(float x) {
    unsigned u = __float_as_uint(x);
    return (unsigned short)((u + 0x7fffu + ((u >> 16) & 1u)) >> 16);
}

// Raw hardware 2^x (bit-identical to OCML exp2 for |x| < 126; compiler
// inserts the trans-op hazard wait-states for the builtin).
__device__ __forceinline__ float fast_exp2(float x) {
#if __has_builtin(__builtin_amdgcn_exp2f)
    return __builtin_amdgcn_exp2f(x);
#else
    return exp2f(x);
#endif
}

typedef __attribute__((address_space(1))) const unsigned int g_u32;
typedef __attribute__((address_space(3))) unsigned int l_u32;
__device__ __forceinline__ void gll16(const void* g, void* l) {
    __builtin_amdgcn_global_load_lds((g_u32*)g, (l_u32*)l, 16, 0, 0);
}

// scale/sqrt(dk) * log2(e), folded into Q so attention P = exp2(e) directly
#define QSCALE 0.1803368801111244f

// ---------------------------------------------------------------------------
// Combined convert launch, grid (4096, 3):
//  y=0: q fp32 -> Xq bf16;  y=1: k fp32 -> Xk bf16
//  y=2: all four weights -> Wt[n][d] bf16 (first 1024 blocks; flat decode)
// ---------------------------------------------------------------------------
__global__ __launch_bounds__(256) void conv_all_kernel(
    const float* __restrict__ q, short* __restrict__ Xq,
    const float* __restrict__ k, short* __restrict__ Xk,
    const float* __restrict__ W0, const float* __restrict__ W1,
    const float* __restrict__ W2, const float* __restrict__ W3,
    short* __restrict__ Wt, int n8) {
    const int tid = threadIdx.x;
    if (blockIdx.y < 2) {
        const int i = blockIdx.x * 256 + tid;
        if (i >= n8) return;
        const float* src = blockIdx.y ? k : q;
        short* dst = blockIdx.y ? Xk : Xq;
        const float4 a = ((const float4*)src)[2 * i];
        const float4 b = ((const float4*)src)[2 * i + 1];
        bf16x8 o;
        o[0] = (short)f2bf(a.x); o[1] = (short)f2bf(a.y);
        o[2] = (short)f2bf(a.z); o[3] = (short)f2bf(a.w);
        o[4] = (short)f2bf(b.x); o[5] = (short)f2bf(b.y);
        o[6] = (short)f2bf(b.z); o[7] = (short)f2bf(b.w);
        ((bf16x8*)dst)[i] = o;
        return;
    }
    // weights slice
    const int flat = blockIdx.x;
    if (flat >= 1024) return;
    __shared__ short t[64][72];
    const int z = flat >> 8;           // 0..3
    const int by = (flat >> 4) & 15;   // d-tile
    const int bx = flat & 15;          // n-tile (or head)
    const float* W = (z == 0) ? W0 : (z == 1) ? W1 : (z == 2) ? W2 : W3;
    short* dst = Wt + (size_t)z * 1024 * 1024;
    const int d0 = by * 64;
    {
        const int r = tid >> 2;
        const int c0 = (tid & 3) * 16;
        const float* srow = (z < 3)
                                ? (W + (size_t)bx * 65536 + (size_t)(d0 + r) * 64 + c0)
                                : (W + (size_t)(d0 + r) * 1024 + bx * 64 + c0);
#pragma unroll
        for (int p = 0; p < 4; ++p) {
            const float4 v = *(const float4*)(srow + p * 4);
            t[r][c0 + p * 4 + 0] = (short)f2bf(v.x);
            t[r][c0 + p * 4 + 1] = (short)f2bf(v.y);
            t[r][c0 + p * 4 + 2] = (short)f2bf(v.z);
            t[r][c0 + p * 4 + 3] = (short)f2bf(v.w);
        }
    }
    __syncthreads();
    {
        const int j = tid >> 2;
        const int c0 = (tid & 3) * 16;
        bf16x8 v0, v1;
#pragma unroll
        for (int p = 0; p < 8; ++p) v0[p] = t[c0 + p][j];
#pragma unroll
        for (int p = 0; p < 8; ++p) v1[p] = t[c0 + 8 + p][j];
        short* drow = dst + (size_t)(bx * 64 + j) * 1024 + d0 + c0;
        *(bf16x8*)drow = v0;
        *(bf16x8*)(drow + 8) = v1;
    }
}

// ---------------------------------------------------------------------------
// Shared GEMM main loop (128x128x64, 4 waves). Single-buffered 2-barrier
// structure — measured optimum of this family (R17 all-F32A +38us, R18
// double-buffer +6us). F32A: A is fp32; all 8 global float4 loads issued
// before cvt/ds_write (one exposed latency).
// ---------------------------------------------------------------------------
template <bool F32A>
__device__ __forceinline__ void gemm_core(const void* __restrict__ Ap,
                                          const short* __restrict__ Bt,
                                          int m0, int n0, int tid,
                                          short* As, short* Bs, f32x4 acc[4][4]) {
    const int w = tid >> 6, lane = tid & 63;
    const int l16 = lane & 15, lk = lane >> 4;
    const int wr = w >> 1, wc = w & 1;
    const int srow = lane >> 3;
    const int schk = lane & 7;
#pragma unroll
    for (int i = 0; i < 4; ++i)
#pragma unroll
        for (int j = 0; j < 4; ++j)
#pragma unroll
            for (int r = 0; r < 4; ++r) acc[i][j][r] = 0.f;

    for (int k0 = 0; k0 < 1024; k0 += 64) {
        if constexpr (!F32A) {
#pragma unroll
            for (int p = 0; p < 4; ++p) {
                const int row = p * 32 + w * 8 + srow;
                const int ca = schk ^ (row & 7);
                gll16(Bt + (size_t)(n0 + row) * 1024 + k0 + ca * 8,
                      &Bs[p * 2048 + w * 512]);
                gll16((const short*)Ap + (size_t)(m0 + row) * 1024 + k0 + ca * 8,
                      &As[p * 2048 + w * 512]);
            }
        } else {
            // (1) async B staging first
#pragma unroll
            for (int p = 0; p < 4; ++p) {
                const int row = p * 32 + w * 8 + srow;
                const int ca = schk ^ (row & 7);
                gll16(Bt + (size_t)(n0 + row) * 1024 + k0 + ca * 8,
                      &Bs[p * 2048 + w * 512]);
            }
            // (2) issue ALL 8 A loads (overlapped latencies)
            float4 st[8];
#pragma unroll
            for (int p = 0; p < 4; ++p) {
                const int row = p * 32 + w * 8 + srow;
                const int ca = schk ^ (row & 7);
                const float* src =
                    (const float*)Ap + (size_t)(m0 + row) * 1024 + k0 + ca * 8;
                st[2 * p] = *(const float4*)src;
                st[2 * p + 1] = *(const float4*)(src + 4);
            }
            // (3) convert + LDS write
#pragma unroll
            for (int p = 0; p < 4; ++p) {
                const float4 lo = st[2 * p];
                const float4 hi = st[2 * p + 1];
                unsigned u0, u1, u2, u3;
                asm("v_cvt_pk_bf16_f32 %0, %1, %2" : "=v"(u0) : "v"(lo.x), "v"(lo.y));
                asm("v_cvt_pk_bf16_f32 %0, %1, %2" : "=v"(u1) : "v"(lo.z), "v"(lo.w));
                asm("v_cvt_pk_bf16_f32 %0, %1, %2" : "=v"(u2) : "v"(hi.x), "v"(hi.y));
                asm("v_cvt_pk_bf16_f32 %0, %1, %2" : "=v"(u3) : "v"(hi.z), "v"(hi.w));
                u32x4 pk;
                pk[0] = u0; pk[1] = u1; pk[2] = u2; pk[3] = u3;
                *(u32x4*)&As[p * 2048 + w * 512 + lane * 8] = pk;
            }
        }
        __syncthreads();
#pragma unroll
        for (int kc = 0; kc < 2; ++kc) {
            bf16x8 a[4], b[4];
#pragma unroll
            for (int mi = 0; mi < 4; ++mi) {
                const int row = wr * 64 + mi * 16 + l16;
                a[mi] = *(const bf16x8*)&As[row * 64 + (((kc * 4 + lk) ^ (row & 7)) * 8)];
            }
#pragma unroll
            for (int ni = 0; ni < 4; ++ni) {
                const int row = wc * 64 + ni * 16 + l16;
                b[ni] = *(const bf16x8*)&Bs[row * 64 + (((kc * 4 + lk) ^ (row & 7)) * 8)];
            }
#pragma unroll
            for (int mi = 0; mi < 4; ++mi)
#pragma unroll
                for (int ni = 0; ni < 4; ++ni)
                    acc[mi][ni] = __builtin_amdgcn_mfma_f32_16x16x32_bf16(
                        a[mi], b[ni], acc[mi][ni], 0, 0, 0);
        }
        __syncthreads();
    }
}

// ---------------------------------------------------------------------------
// Q, K and V projections in ONE launch (grid.z = 0:Q, 1:K, 2:V).
// ---------------------------------------------------------------------------
__global__ __launch_bounds__(256) void gemm_qkv_kernel(
    const short* __restrict__ Xq, const short* __restrict__ Xk,
    const float* __restrict__ Vf, const short* __restrict__ Wt,
    const float* __restrict__ bq, const float* __restrict__ bk,
    const float* __restrict__ bv, short* __restrict__ Qp,
    short* __restrict__ Kp, short* __restrict__ VTp) {
    __shared__ short As[8192];
    __shared__ short Bs[8192];
    const int z = blockIdx.z;
    const int id = blockIdx.x;
    const int swz = (id & 7) * 64 + (id >> 3);
    const int n0 = (swz & 7) * 128;
    const int m0 = (swz >> 3) * 128;
    const int tid = threadIdx.x;
    const int w = tid >> 6, lane = tid & 63;
    const int l16 = lane & 15, lk = lane >> 4;
    const int wr = w >> 1, wc = w & 1;
    const size_t WSEG = (size_t)1024 * 1024;

    f32x4 acc[4][4];
    if (z == 0)
        gemm_core<false>(Xq, Wt, m0, n0, tid, As, Bs, acc);
    else if (z == 1)
        gemm_core<false>(Xk, Wt + WSEG, m0, n0, tid, As, Bs, acc);
    else
        gemm_core<true>(Vf, Wt + 2 * WSEG, m0, n0, tid, As, Bs, acc);

    const float* bias = (z == 0) ? bq : (z == 1) ? bk : bv;
#pragma unroll
    for (int mi = 0; mi < 4; ++mi) {
        const int gm0 = m0 + wr * 64 + mi * 16 + lk * 4;
#pragma unroll
        for (int ni = 0; ni < 4; ++ni) {
            const int gn = n0 + wc * 64 + ni * 16 + l16;
            const float bv_ = bias[gn];
            if (z == 0) {
                const float bvs = bv_ * QSCALE;
#pragma unroll
                for (int r = 0; r < 4; ++r) {
                    const int gm = gm0 + r;
                    Qp[((size_t)((gm >> 11) * 16 + (gn >> 6)) * 2048 + (gm & 2047)) * 64 +
                       (gn & 63)] = (short)f2bf(fmaf(acc[mi][ni][r], QSCALE, bvs));
                }
            } else if (z == 1) {
#pragma unroll
                for (int r = 0; r < 4; ++r) {
                    const int gm = gm0 + r;
                    const int t = gm & 2047;
                    const int j = gn & 63;
                    const int jsw = (((j >> 3) ^ (t & 7)) << 3) | (j & 7);
                    Kp[((size_t)((gm >> 11) * 16 + (gn >> 6)) * 2048 + t) * 64 + jsw] =
                        (short)f2bf(acc[mi][ni][r] + bv_);
                }
            } else {  // V -> VT, pack 4 consecutive t
                s16x4 pk;
#pragma unroll
                for (int r = 0; r < 4; ++r) pk[r] = (short)f2bf(acc[mi][ni][r] + bv_);
                const int t0 = gm0 & 2047;
                const int j = gn & 63;
                const int tsw = (t0 & ~63) | ((((t0 >> 3) & 7) ^ (j & 7)) << 3) | (t0 & 7);
                *(s16x4*)&VTp[(((size_t)((gm0 >> 11) * 16 + (gn >> 6))) * 64 + j) * 2048 +
                              tsw] = pk;
            }
        }
    }
}

// ---------------------------------------------------------------------------
// Final output projection: fp32 out [m][n]
// ---------------------------------------------------------------------------
__global__ __launch_bounds__(256) void gemm_out_kernel(
    const short* __restrict__ A, const short* __restrict__ Bt,
    const float* __restrict__ bias, float* __restrict__ outf) {
    __shared__ short As[8192];
    __shared__ short Bs[8192];
    const int id = blockIdx.x;
    const int swz = (id & 7) * 64 + (id >> 3);
    const int n0 = (swz & 7) * 128;
    const int m0 = (swz >> 3) * 128;
    const int tid = threadIdx.x;
    const int w = tid >> 6, lane = tid & 63;
    const int l16 = lane & 15, lk = lane >> 4;
    const int wr = w >> 1, wc = w & 1;

    f32x4 acc[4][4];
    gemm_core<false>(A, Bt, m0, n0, tid, As, Bs, acc);

#pragma unroll
    for (int mi = 0; mi < 4; ++mi) {
        const int gm0 = m0 + wr * 64 + mi * 16 + lk * 4;
#pragma unroll
        for (int ni = 0; ni < 4; ++ni) {
            const int gn = n0 + wc * 64 + ni * 16 + l16;
            const float bv = bias[gn];
#pragma unroll
            for (int r = 0; r < 4; ++r)
                outf[(size_t)(gm0 + r) * 1024 + gn] = acc[mi][ni][r] + bv;
        }
    }
}

// ---------------------------------------------------------------------------
// Attention per-tile compute, NB = compile-time buffer index so every
// ds_read is base-pointer + immediate.
// ---------------------------------------------------------------------------
template <int NB>
__device__ __forceinline__ void attn_tile(const short* __restrict__ smf,
                                          const int* __restrict__ ro,
                                          const bf16x8* __restrict__ qf,
                                          f32x16* __restrict__ acc,
                                          float& ts_acc) {
    u32x4 pa[4];  // PV A-frags
#pragma unroll
    for (int sb = 0; sb < 2; ++sb) {
        f32x16 e;
#pragma unroll
        for (int r = 0; r < 16; ++r) e[r] = 0.f;
        __builtin_amdgcn_s_setprio(1);
#pragma unroll
        for (int sl = 0; sl < 4; ++sl) {
            const bf16x8 kf = *(const bf16x8*)&smf[ro[sb * 4 + sl] + NB * 8192];
            e = __builtin_amdgcn_mfma_f32_32x32x16_bf16(kf, qf[sl], e, 0, 0, 0);
        }
        __builtin_amdgcn_s_setprio(0);
        // p = exp2(e); rows held: s = (reg&3) + 8*(reg>>2) + 4*hi (+32*sb)
        float p[16];
#pragma unroll
        for (int r = 0; r < 16; ++r) p[r] = fast_exp2(e[r]);
#pragma unroll
        for (int r = 0; r < 16; r += 4)
            ts_acc += ((p[r] + p[r + 1]) + (p[r + 2] + p[r + 3]));
        unsigned u[4][2];
#pragma unroll
        for (int A = 0; A < 4; ++A)
#pragma unroll
            for (int b = 0; b < 2; ++b)
                asm("v_cvt_pk_bf16_f32 %0, %1, %2"
                    : "=v"(u[A][b])
                    : "v"(p[4 * A + 2 * b]), "v"(p[4 * A + 2 * b + 1]));
#pragma unroll
        for (int k1 = 0; k1 < 2; ++k1) {
#pragma unroll
            for (int b = 0; b < 2; ++b) {
                unsigned p0 = u[2 * k1][b], p1 = u[2 * k1 + 1][b];
                asm("v_permlane32_swap_b32 %0, %1" : "+v"(p0), "+v"(p1));
                pa[sb * 2 + k1][b] = p0;
                pa[sb * 2 + k1][2 + b] = p1;
            }
        }
    }
    // PV: A = P (row q = l31, k = s), B = V^T tile (col v = l31)
    __builtin_amdgcn_s_setprio(1);
#pragma unroll
    for (int vb = 0; vb < 2; ++vb) {
#pragma unroll
        for (int ks = 0; ks < 4; ++ks) {
            const bf16x8 vf =
                *(const bf16x8*)&smf[ro[vb * 4 + ks] + NB * 8192 + 4096];
            const bf16x8 paf = __builtin_bit_cast(bf16x8, pa[ks]);
            acc[vb] = __builtin_amdgcn_mfma_f32_32x32x16_bf16(paf, vf, acc[vb],
                                                              0, 0, 0);
        }
    }
    __builtin_amdgcn_s_setprio(0);
}

// ---------------------------------------------------------------------------
// Flash attention — raw v_exp_f32, hoisted LDS addressing, double-buffered
// prefetch, 512 thr x 512 blocks.
// ---------------------------------------------------------------------------
__global__ __launch_bounds__(512, 4) void attn_kernel(
    const short* __restrict__ Qp, const short* __restrict__ Kp,
    const short* __restrict__ VTp, short* __restrict__ heads) {
    __shared__ short smem[4][4096];  // [nb][kv][64x64 tile]
    short* smf = &smem[0][0];
    const int tid = threadIdx.x;
    const int w = tid >> 6, lane = tid & 63;
    const int l31 = lane & 31, hi = lane >> 5;
    const int id = blockIdx.x;
    const int swz = (id & 7) * 64 + (id >> 3);  // 512 blocks, XCD-contiguous
    const int qbase = (swz & 7) * 256;          // 8 blocks per bh
    const int bh = swz >> 3;
    const size_t kvbase = (size_t)bh * TT * 64;

    // Q B-fragments: col q = l31, k(d) = sl*16 + hi*8 + j
    bf16x8 qf[4];
    {
        const short* Qw = Qp + kvbase + (size_t)(qbase + w * 32 + l31) * 64 + hi * 8;
#pragma unroll
        for (int sl = 0; sl < 4; ++sl) qf[sl] = *(const bf16x8*)(Qw + sl * 16);
    }

    f32x16 acc[2];
#pragma unroll
    for (int vb = 0; vb < 2; ++vb)
#pragma unroll
        for (int r = 0; r < 16; ++r) acc[vb][r] = 0.f;
    float ts_acc = 0.f;  // per-lane partial of sum_s P[q=l31][s]

    // per-lane read offsets, slot (sb,sl): (sb*32+l31)*64 + ((sl*2+hi)^(l31&7))*8
    int ro[8];
#pragma unroll
    for (int sb = 0; sb < 2; ++sb)
#pragma unroll
        for (int sl = 0; sl < 4; ++sl)
            ro[sb * 4 + sl] =
                (sb * 32 + l31) * 64 + (((sl * 2 + hi) ^ (l31 & 7)) * 8);

    // staging: incrementing global pointers; LDS dst compile-time per phase
    const int strow = w * 8 + (lane >> 3);
    const int sca = lane & 7;  // source pre-swizzled -> linear copy
    const short* gK = Kp + kvbase + (size_t)strow * 64 + sca * 8;    // +4096/tile
    const short* gV = VTp + kvbase + (size_t)strow * 2048 + sca * 8; // +64/tile
    short* lK0 = smf + 0 + w * 512;
    short* lV0 = smf + 4096 + w * 512;
    short* lK1 = smf + 8192 + w * 512;
    short* lV1 = smf + 12288 + w * 512;

    // prologue: stage tile 0 into buf0
    gll16(gK, lK0);
    gll16(gV, lV0);
    __syncthreads();

    for (int it = 0; it < 16; ++it) {
        // phase 0: stage tile 2it+1 -> buf1, compute buf0 (tile 2it)
        gK += 4096;
        gV += 64;
        gll16(gK, lK1);
        gll16(gV, lV1);
        attn_tile<0>(smf, ro, qf, acc, ts_acc);
        __syncthreads();
        // phase 1: stage tile 2it+2 -> buf0 (unless done), compute buf1
        if (it < 15) {
            gK += 4096;
            gV += 64;
            gll16(gK, lK0);
            gll16(gV, lV0);
        }
        attn_tile<1>(smf, ro, qf, acc, ts_acc);
        __syncthreads();
    }

    // l per q: combine wave halves (lane q and q+32 hold the two halves)
    float l = ts_acc;
    l += __shfl_xor(l, 32);
    const float linv = 1.0f / l;
    const int b_ = bh >> 4, h = bh & 15;
#pragma unroll
    for (int r = 0; r < 16; ++r) {
        const int qrow = (r & 3) + 8 * (r >> 2) + 4 * hi;
        const float inv = __shfl(linv, qrow);
        const int qg = qbase + w * 32 + qrow;
        const size_t base = ((size_t)(b_ * TT + qg)) * 1024 + h * 64 + l31;
        heads[base] = (short)f2bf(acc[0][r] * inv);
        heads[base + 32] = (short)f2bf(acc[1][r] * inv);
    }
}

extern "C" void kernel_launch(void* const* d_in, const int* in_sizes, int n_in,
                              void* d_out, int out_size, void* d_ws, size_t ws_size,
                              hipStream_t stream) {
    const float* q = (const float*)d_in[0];
    const float* k = (const float*)d_in[1];
    const float* v = (const float*)d_in[2];
    const float* Wq = (const float*)d_in[3];
    const float* bq = (const float*)d_in[4];
    const float* Wk = (const float*)d_in[5];
    const float* bk = (const float*)d_in[6];
    const float* Wv = (const float*)d_in[7];
    const float* bv = (const float*)d_in[8];
    const float* Wo = (const float*)d_in[9];
    const float* bo = (const float*)d_in[10];
    float* out = (float*)d_out;

    const size_t SEG = (size_t)4 * 16 * 2048 * 64;  // 8,388,608 bf16 elems
    // d_out (33.5 MB): Qp | Kp until the final GEMM overwrites with fp32 out.
    short* Qp = (short*)d_out;
    short* Kp = Qp + SEG;
    // ws: Xq | Xk | Wt x4 | VTp  (= 56 MB)
    short* ws = (short*)d_ws;
    short* Xq = ws;  // later reused for heads
    short* Xk = Xq + SEG;
    short* Wt = Xk + SEG;
    short* VTp = Wt + (size_t)4 * 1024 * 1024;
    const size_t WSEG = (size_t)1024 * 1024;

    dim3 blk(256);
    const int n8 = (int)(SEG / 8);

    conv_all_kernel<<<dim3((n8 + 255) / 256, 3), blk, 0, stream>>>(
        q, Xq, k, Xk, Wq, Wk, Wv, Wo, Wt, n8);
    gemm_qkv_kernel<<<dim3(512, 1, 3), blk, 0, stream>>>(Xq, Xk, v, Wt, bq, bk, bv,
                                                         Qp, Kp, VTp);
    attn_kernel<<<dim3(512), dim3(512), 0, stream>>>(Qp, Kp, VTp, Xq /*heads*/);
    gemm_out_kernel<<<dim3(512), blk, 0, stream>>>(Xq, Wt + 3 * WSEG, bo, out);
}